// Round 4
// baseline (561.518 us; speedup 1.0000x reference)
//
#include <hip/hip_runtime.h>
#include <hip/hip_bf16.h>

// GPSA (ConViT gated positional self-attention), B=8 N=784 DIM=384 H=12 d=32.
//
// Round-4: inputs are f32 (proven by R1: bf16-misread -> exp-overflow NaN);
// OUTPUT IS F32 (R2/R3 bit-identical absmax 0.84765625 despite bf16-ws
// perturbation == signature of packed-bf16-read-as-f32; harness doc: output
// dtype per reference = float32). This round's single semantic change: the
// final store is float4 f32. Intermediates stay bf16 in ws (R3 showed the
// argmax output is bit-identical vs f32 ws; ~0.3% rounding vs 2% budget).
//
// Math notes:
//  * attn row-sum == 1 exactly ((1-g)+g), so reference's renormalize is a no-op.
//  * logits bounded above (~2) -> single-pass softmax, no max subtraction;
//    exp args clamped to <=30 as NaN insurance (inert for correct data).

#define MDIM 6272   // B*N
#define KDIM 384    // DIM
#define NPAT 784
#define SGRID 28
#define NH 12
#define HD 32
#define BM 64
#define BN 64
#define BK 32
#define AT_TM 112   // 784 = 7*112

typedef unsigned short u16;

__device__ __forceinline__ float bf2f(u16 u) {
    union { unsigned i; float f; } v; v.i = ((unsigned)u) << 16; return v.f;
}
__device__ __forceinline__ u16 f2bf(float f) {
    union { float f; unsigned u; } v; v.f = f;
    unsigned u = v.u;
    u += 0x7fffu + ((u >> 16) & 1u);   // round-to-nearest-even
    return (u16)(u >> 16);
}

// ---------------- QKV projection: C = x @ W^T, stored permuted [3][96][784][32] bf16
__global__ __launch_bounds__(256) void qkv_gemm(
    const float* __restrict__ x,    // [6272][384] f32
    const float* __restrict__ Wq,
    const float* __restrict__ Wk,
    const float* __restrict__ Wv,
    u16* __restrict__ outb)         // [3][96][784][32] bf16
{
    __shared__ float As[BK][BM];
    __shared__ float Bs[BK][BN];

    const int mat = blockIdx.z;
    const float* W = (mat == 0) ? Wq : (mat == 1) ? Wk : Wv;
    u16* dst = outb + (size_t)mat * ((size_t)MDIM * KDIM);

    const int tid = threadIdx.x;
    const int im0 = blockIdx.x * BM;
    const int jn0 = blockIdx.y * BN;
    const int tx = tid & 15, ty = tid >> 4;
    const int r  = tid >> 2;            // 0..63
    const int c8 = (tid & 3) << 3;      // 0,8,16,24

    float acc[4][4] = {};

    for (int k0 = 0; k0 < KDIM; k0 += BK) {
        float4 a0 = *(const float4*)(x + (size_t)(im0 + r) * KDIM + k0 + c8);
        float4 a1 = *(const float4*)(x + (size_t)(im0 + r) * KDIM + k0 + c8 + 4);
        float4 b0 = *(const float4*)(W + (size_t)(jn0 + r) * KDIM + k0 + c8);
        float4 b1 = *(const float4*)(W + (size_t)(jn0 + r) * KDIM + k0 + c8 + 4);
        As[c8+0][r] = a0.x; As[c8+1][r] = a0.y; As[c8+2][r] = a0.z; As[c8+3][r] = a0.w;
        As[c8+4][r] = a1.x; As[c8+5][r] = a1.y; As[c8+6][r] = a1.z; As[c8+7][r] = a1.w;
        Bs[c8+0][r] = b0.x; Bs[c8+1][r] = b0.y; Bs[c8+2][r] = b0.z; Bs[c8+3][r] = b0.w;
        Bs[c8+4][r] = b1.x; Bs[c8+5][r] = b1.y; Bs[c8+6][r] = b1.z; Bs[c8+7][r] = b1.w;
        __syncthreads();
        #pragma unroll
        for (int kk = 0; kk < BK; ++kk) {
            float4 a = *(const float4*)&As[kk][ty << 2];
            float4 b = *(const float4*)&Bs[kk][tx << 2];
            float av[4] = {a.x, a.y, a.z, a.w};
            float bv[4] = {b.x, b.y, b.z, b.w};
            #pragma unroll
            for (int i = 0; i < 4; ++i)
                #pragma unroll
                for (int j = 0; j < 4; ++j)
                    acc[i][j] += av[i] * bv[j];
        }
        __syncthreads();
    }

    // store permuted: row i=(b*784+n), col j=(h*32+d) -> dst[((b*12+h)*784+n)*32+d]
    const int j0 = jn0 + (tx << 2);
    const int hh = j0 >> 5;
    const int d0 = j0 & 31;
    #pragma unroll
    for (int i = 0; i < 4; ++i) {
        int gi = im0 + (ty << 2) + i;
        int bb = gi / NPAT;
        int nn = gi - bb * NPAT;
        ushort4 st;
        st.x = f2bf(acc[i][0]); st.y = f2bf(acc[i][1]);
        st.z = f2bf(acc[i][2]); st.w = f2bf(acc[i][3]);
        *(ushort4*)&dst[(((size_t)bb * NH + hh) * NPAT + nn) * HD + d0] = st;
    }
}

// ---------------- Fused dual-softmax attention ---------------------------------
// One thread per query row; 112 rows/block; K/V tiles (112x32) bf16->f32 in LDS.
//   out_row = (1-g)/l1 * sum_m e^{s(m)} v[m]  +  g/l2 * sum_m e^{p(m)} v[m]
__global__ __launch_bounds__(128) void attn_kernel(
    const u16* __restrict__ qkvb,      // [3][96][784][32] bf16
    const float* __restrict__ W_pos,   // [12][3] f32
    const float* __restrict__ b_pos,   // [12] f32
    const float* __restrict__ gating,  // [12] f32
    u16* __restrict__ ob)              // [6272][384] bf16, [b][n][h*32+d]
{
    __shared__ float k_s[AT_TM * HD];
    __shared__ float v_s[AT_TM * HD];

    const int bh = blockIdx.y;               // b*12+h
    const int bb = bh / NH;
    const int hh = bh - bb * NH;
    const int tid = threadIdx.x;
    const int n = blockIdx.x * AT_TM + tid;
    const bool active = tid < AT_TM;

    const float c0 = W_pos[hh * 3 + 0];
    const float c1 = W_pos[hh * 3 + 1];
    const float c2 = W_pos[hh * 3 + 2];
    const float bp = b_pos[hh];
    const float gf = gating[hh];
    const float g  = 1.0f / (1.0f + __expf(-gf));
    const float scale = 0.28867513459481287f;   // 12^-0.5

    const size_t S = (size_t)MDIM * KDIM;
    const u16* qp = qkvb +         ((size_t)bh * NPAT) * HD;
    const u16* kp = qkvb + S +     ((size_t)bh * NPAT) * HD;
    const u16* vp = qkvb + 2*S +   ((size_t)bh * NPAT) * HD;

    float q_r[HD];
    int nx = 0, ny = 0;
    if (active) {
        ny = n / SGRID; nx = n - ny * SGRID;
        const uint4* qg = (const uint4*)(qp + (size_t)n * HD);
        #pragma unroll
        for (int d4 = 0; d4 < 4; ++d4) {
            uint4 t = qg[d4];
            unsigned wq[4] = {t.x, t.y, t.z, t.w};
            #pragma unroll
            for (int q = 0; q < 4; ++q) {
                q_r[d4*8 + 2*q + 0] = bf2f((u16)(wq[q] & 0xffffu)) * scale;
                q_r[d4*8 + 2*q + 1] = bf2f((u16)(wq[q] >> 16)) * scale;
            }
        }
    }

    float o1[HD] = {};
    float o2[HD] = {};
    float l1 = 0.0f, l2 = 0.0f;

    for (int mt = 0; mt < NPAT / AT_TM; ++mt) {
        const int mbase = mt * AT_TM;
        // stage K/V tile: 112*32 bf16 = 448 uint4 groups of 8
        const uint4* kg = (const uint4*)(kp + (size_t)mbase * HD);
        const uint4* vg = (const uint4*)(vp + (size_t)mbase * HD);
        #pragma unroll
        for (int it = 0; it < 4; ++it) {
            int f = it * 128 + tid;
            if (f < 448) {
                uint4 tk = kg[f];
                uint4 tv = vg[f];
                unsigned wk[4] = {tk.x, tk.y, tk.z, tk.w};
                unsigned wv[4] = {tv.x, tv.y, tv.z, tv.w};
                #pragma unroll
                for (int q = 0; q < 4; ++q) {
                    k_s[f*8 + 2*q + 0] = bf2f((u16)(wk[q] & 0xffffu));
                    k_s[f*8 + 2*q + 1] = bf2f((u16)(wk[q] >> 16));
                    v_s[f*8 + 2*q + 0] = bf2f((u16)(wv[q] & 0xffffu));
                    v_s[f*8 + 2*q + 1] = bf2f((u16)(wv[q] >> 16));
                }
            }
        }
        __syncthreads();
        if (active) {
            for (int mm = 0; mm < AT_TM; ++mm) {
                int m = mbase + mm;                 // uniform -> scalarized
                int my = m / SGRID;
                int mx = m - my * SGRID;
                float fdx = (float)(mx - nx);
                float fdy = (float)(my - ny);
                float p = c0 * fdx + c1 * fdy + c2 * (fdx * fdx + fdy * fdy) + bp;

                const float* krow = &k_s[mm * HD];
                float s = 0.0f;
                #pragma unroll
                for (int d = 0; d < HD; ++d) s += q_r[d] * krow[d];

                float e1 = __expf(fminf(s, 30.0f));   // clamp: inert for correct data
                float e2 = __expf(fminf(p, 30.0f));
                l1 += e1; l2 += e2;

                const float* vrow = &v_s[mm * HD];
                #pragma unroll
                for (int d = 0; d < HD; ++d) {
                    o1[d] += e1 * vrow[d];
                    o2[d] += e2 * vrow[d];
                }
            }
        }
        __syncthreads();
    }

    if (active) {
        const float w1 = (1.0f - g) / l1;
        const float w2 = g / l2;
        u16* op = ob + ((size_t)bb * NPAT + n) * KDIM + hh * HD;
        #pragma unroll
        for (int d4 = 0; d4 < 8; ++d4) {
            ushort4 st;
            st.x = f2bf(w1 * o1[d4*4+0] + w2 * o2[d4*4+0]);
            st.y = f2bf(w1 * o1[d4*4+1] + w2 * o2[d4*4+1]);
            st.z = f2bf(w1 * o1[d4*4+2] + w2 * o2[d4*4+2]);
            st.w = f2bf(w1 * o1[d4*4+3] + w2 * o2[d4*4+3]);
            *(ushort4*)&op[d4 * 4] = st;
        }
    }
}

// ---------------- Output projection: out = A @ Wo^T + b, **f32 store** ---------
__global__ __launch_bounds__(256) void out_gemm(
    const u16* __restrict__ A,        // [6272][384] bf16 (attention output in ws)
    const float* __restrict__ Wo,     // [384][384] f32
    const float* __restrict__ bias,   // [384] f32
    float* __restrict__ out)          // [6272][384] f32  <-- THE fix this round
{
    __shared__ float As[BK][BM];
    __shared__ float Bs[BK][BN];

    const int tid = threadIdx.x;
    const int im0 = blockIdx.x * BM;
    const int jn0 = blockIdx.y * BN;
    const int tx = tid & 15, ty = tid >> 4;
    const int r  = tid >> 2;
    const int c8 = (tid & 3) << 3;

    float acc[4][4] = {};

    for (int k0 = 0; k0 < KDIM; k0 += BK) {
        {   // A is bf16 in ws
            uint4 ra = *(const uint4*)(A + (size_t)(im0 + r) * KDIM + k0 + c8);
            unsigned wa[4] = {ra.x, ra.y, ra.z, ra.w};
            #pragma unroll
            for (int q = 0; q < 4; ++q) {
                As[c8 + 2*q + 0][r] = bf2f((u16)(wa[q] & 0xffffu));
                As[c8 + 2*q + 1][r] = bf2f((u16)(wa[q] >> 16));
            }
        }
        float4 b0 = *(const float4*)(Wo + (size_t)(jn0 + r) * KDIM + k0 + c8);
        float4 b1 = *(const float4*)(Wo + (size_t)(jn0 + r) * KDIM + k0 + c8 + 4);
        Bs[c8+0][r] = b0.x; Bs[c8+1][r] = b0.y; Bs[c8+2][r] = b0.z; Bs[c8+3][r] = b0.w;
        Bs[c8+4][r] = b1.x; Bs[c8+5][r] = b1.y; Bs[c8+6][r] = b1.z; Bs[c8+7][r] = b1.w;
        __syncthreads();
        #pragma unroll
        for (int kk = 0; kk < BK; ++kk) {
            float4 a = *(const float4*)&As[kk][ty << 2];
            float4 b = *(const float4*)&Bs[kk][tx << 2];
            float av[4] = {a.x, a.y, a.z, a.w};
            float bv[4] = {b.x, b.y, b.z, b.w};
            #pragma unroll
            for (int i = 0; i < 4; ++i)
                #pragma unroll
                for (int j = 0; j < 4; ++j)
                    acc[i][j] += av[i] * bv[j];
        }
        __syncthreads();
    }

    const int j0 = jn0 + (tx << 2);
    float bv[4];
    #pragma unroll
    for (int j = 0; j < 4; ++j) bv[j] = bias[j0 + j];
    #pragma unroll
    for (int i = 0; i < 4; ++i) {
        int gi = im0 + (ty << 2) + i;
        float4 st = make_float4(acc[i][0] + bv[0], acc[i][1] + bv[1],
                                acc[i][2] + bv[2], acc[i][3] + bv[3]);
        *(float4*)&out[(size_t)gi * KDIM + j0] = st;
    }
}

extern "C" void kernel_launch(void* const* d_in, const int* in_sizes, int n_in,
                              void* d_out, int out_size, void* d_ws, size_t ws_size,
                              hipStream_t stream) {
    const float* x    = (const float*)d_in[0];
    const float* Wq   = (const float*)d_in[1];
    const float* Wk   = (const float*)d_in[2];
    const float* Wv   = (const float*)d_in[3];
    const float* Wpos = (const float*)d_in[4];
    const float* bpos = (const float*)d_in[5];
    const float* Wout = (const float*)d_in[6];
    const float* bout = (const float*)d_in[7];
    const float* gat  = (const float*)d_in[8];

    // ws layout (19.27 MB total):
    //   [0]      u16 qkv[3][96][784][32]   (14,450,688 B)
    //   [+qkv]   u16 o[6272][384]          ( 4,816,896 B)
    u16* qkvb = (u16*)d_ws;
    u16* ob   = qkvb + (size_t)3 * MDIM * KDIM;

    qkv_gemm<<<dim3(MDIM / BM, KDIM / BN, 3), 256, 0, stream>>>(x, Wq, Wk, Wv, qkvb);
    attn_kernel<<<dim3(NPAT / AT_TM, 96), 128, 0, stream>>>(qkvb, Wpos, bpos, gat, ob);
    out_gemm<<<dim3(MDIM / BM, KDIM / BN), 256, 0, stream>>>(ob, Wout, bout, (float*)d_out);
}

// Round 5
// 272.983 us; speedup vs baseline: 2.0570x; 2.0570x over previous
//
#include <hip/hip_runtime.h>
#include <hip/hip_bf16.h>

// GPSA (ConViT gated positional self-attention), B=8 N=784 DIM=384 H=12 d=32.
// f32 inputs, f32 output (established R4). Round-5: MFMA attention.
//   qkv_gemm: x@W^T -> Q,K as bf16 [96][784][32]; V stored TRANSPOSED [96][32][784]
//   attn_mfma: per wave = 16 queries x 784 keys, dual-softmax streams:
//     S^T = K·Q^T via mfma_f32_16x16x32_bf16 (C: col=lane&15=query, row=quad*4+reg=key)
//     e1: exp in C-layout -> LDS round-trip -> A-layout frags (m120 pattern)
//     e2 (pos stream): computed directly in A-layout registers (no LDS)
//     PV: mfma_f32_16x16x32_bf16, V^T rows give contiguous B-frags
//   out_gemm: unchanged (f32 store).
// Math: attn row-sum == 1 ((1-g)+g) -> renormalize skipped; logits bounded above
// -> single-pass softmax, exp2-domain with clamp as NaN insurance.

#define MDIM 6272   // B*N
#define KDIM 384    // DIM
#define NPAT 784
#define SGRID 28
#define NH 12
#define HD 32
#define BM 64
#define BN 64
#define BK 32

typedef unsigned short u16;
typedef __attribute__((ext_vector_type(8))) short bf16x8;
typedef __attribute__((ext_vector_type(4))) float f32x4;

__device__ __forceinline__ u16 f2bf(float f) {
    union { float f; unsigned u; } v; v.f = f;
    unsigned u = v.u;
    u += 0x7fffu + ((u >> 16) & 1u);   // round-to-nearest-even
    return (u16)(u >> 16);
}

// ---------------- QKV projection: C = x @ W^T --------------------------------
// mat 0/1 (Q,K): store [96][784][32] bf16. mat 2 (V): store transposed [96][32][784].
__global__ __launch_bounds__(256) void qkv_gemm(
    const float* __restrict__ x,    // [6272][384] f32
    const float* __restrict__ Wq,
    const float* __restrict__ Wk,
    const float* __restrict__ Wv,
    u16* __restrict__ outb)
{
    __shared__ float As[BK][BM];
    __shared__ float Bs[BK][BN];

    const int mat = blockIdx.z;
    const float* W = (mat == 0) ? Wq : (mat == 1) ? Wk : Wv;
    const size_t S = (size_t)96 * NPAT * HD;
    u16* dst = outb + (size_t)mat * S;

    const int tid = threadIdx.x;
    const int im0 = blockIdx.x * BM;
    const int jn0 = blockIdx.y * BN;
    const int tx = tid & 15, ty = tid >> 4;
    const int r  = tid >> 2;            // 0..63
    const int c8 = (tid & 3) << 3;      // 0,8,16,24

    float acc[4][4] = {};

    for (int k0 = 0; k0 < KDIM; k0 += BK) {
        float4 a0 = *(const float4*)(x + (size_t)(im0 + r) * KDIM + k0 + c8);
        float4 a1 = *(const float4*)(x + (size_t)(im0 + r) * KDIM + k0 + c8 + 4);
        float4 b0 = *(const float4*)(W + (size_t)(jn0 + r) * KDIM + k0 + c8);
        float4 b1 = *(const float4*)(W + (size_t)(jn0 + r) * KDIM + k0 + c8 + 4);
        As[c8+0][r] = a0.x; As[c8+1][r] = a0.y; As[c8+2][r] = a0.z; As[c8+3][r] = a0.w;
        As[c8+4][r] = a1.x; As[c8+5][r] = a1.y; As[c8+6][r] = a1.z; As[c8+7][r] = a1.w;
        Bs[c8+0][r] = b0.x; Bs[c8+1][r] = b0.y; Bs[c8+2][r] = b0.z; Bs[c8+3][r] = b0.w;
        Bs[c8+4][r] = b1.x; Bs[c8+5][r] = b1.y; Bs[c8+6][r] = b1.z; Bs[c8+7][r] = b1.w;
        __syncthreads();
        #pragma unroll
        for (int kk = 0; kk < BK; ++kk) {
            float4 a = *(const float4*)&As[kk][ty << 2];
            float4 b = *(const float4*)&Bs[kk][tx << 2];
            float av[4] = {a.x, a.y, a.z, a.w};
            float bv[4] = {b.x, b.y, b.z, b.w};
            #pragma unroll
            for (int i = 0; i < 4; ++i)
                #pragma unroll
                for (int j = 0; j < 4; ++j)
                    acc[i][j] += av[i] * bv[j];
        }
        __syncthreads();
    }

    const int j0 = jn0 + (tx << 2);
    const int hh = j0 >> 5;
    const int d0 = j0 & 31;
    const int n0 = im0 + (ty << 2);
    const int bb = n0 / NPAT;           // 4-aligned rows never cross batch (784=4*196)
    const int nn = n0 - bb * NPAT;

    if (mat < 2) {
        #pragma unroll
        for (int i = 0; i < 4; ++i) {
            ushort4 st;
            st.x = f2bf(acc[i][0]); st.y = f2bf(acc[i][1]);
            st.z = f2bf(acc[i][2]); st.w = f2bf(acc[i][3]);
            *(ushort4*)&dst[(((size_t)bb * NH + hh) * NPAT + nn + i) * HD + d0] = st;
        }
    } else {
        // V^T[bh][d][n]
        #pragma unroll
        for (int j = 0; j < 4; ++j) {
            ushort4 st;
            st.x = f2bf(acc[0][j]); st.y = f2bf(acc[1][j]);
            st.z = f2bf(acc[2][j]); st.w = f2bf(acc[3][j]);
            *(ushort4*)&dst[(((size_t)bb * NH + hh) * HD + d0 + j) * NPAT + nn] = st;
        }
    }
}

// ---------------- MFMA dual-softmax attention --------------------------------
// 1 wave (64 threads) per block; block = (qt, bh): 16 queries x all 784 keys.
__global__ __launch_bounds__(64) void attn_mfma(
    const u16* __restrict__ qkvb,      // Q | K [96][784][32], V^T [96][32][784]
    const float* __restrict__ W_pos,   // [12][3] f32
    const float* __restrict__ b_pos,   // [12] f32
    const float* __restrict__ gating,  // [12] f32
    u16* __restrict__ ob)              // [6272][384] bf16, [b][n][h*32+d]
{
    __shared__ u16 Pb[16][40];   // e1 staging, padded stride 40 halves (80 B)

    const int qt = blockIdx.x;         // 0..48
    const int bh = blockIdx.y;         // 0..95
    const int bb = bh / NH;
    const int hh = bh - bb * NH;
    const int lane = threadIdx.x;
    const int col = lane & 15;
    const int quad = lane >> 4;

    const float L2E = 1.4426950408889634f;
    const float SCL = 0.28867513459481287f * L2E;   // 12^-0.5 * log2(e)
    const float c0 = W_pos[hh * 3 + 0] * L2E;
    const float c1 = W_pos[hh * 3 + 1] * L2E;
    const float c2 = W_pos[hh * 3 + 2] * L2E;
    const float bp = b_pos[hh] * L2E;
    const float g  = 1.0f / (1.0f + __expf(-gating[hh]));

    const size_t S = (size_t)96 * NPAT * HD;
    const u16* Qp = qkvb + (size_t)bh * NPAT * HD;
    const u16* Kp = Qp + S;
    const u16* Vt = qkvb + 2 * S + (size_t)bh * HD * NPAT;  // rows of length NPAT

    const int q_n = qt * 16 + col;
    const int ny = q_n / SGRID;
    const int nx = q_n - ny * SGRID;

    // B-frag of Q: lane&15 = query col, k = quad*8+j = head dim (contiguous 16B)
    const bf16x8 qf = *(const bf16x8*)(Qp + (size_t)q_n * HD + quad * 8);

    f32x4 a1lo = {0,0,0,0}, a1hi = {0,0,0,0};   // patch stream PV acc (d 0-15 / 16-31)
    f32x4 a2lo = {0,0,0,0}, a2hi = {0,0,0,0};   // pos   stream PV acc
    float l1 = 0.0f, l2 = 0.0f;

    for (int G = 0; G < 25; ++G) {              // 32-key groups; G=24 is 16-key tail
        const int key0 = G * 32;

        // --- QK^T (S^T = K·Q^T) + exp -> LDS (A-layout for PV) ---
        #pragma unroll
        for (int half = 0; half < 2; ++half) {
            const int kt = key0 + half * 16;
            if (kt < NPAT) {
                bf16x8 kf = *(const bf16x8*)(Kp + (size_t)(kt + col) * HD + quad * 8);
                f32x4 c = __builtin_amdgcn_mfma_f32_16x16x32_bf16(kf, qf, (f32x4){0,0,0,0}, 0, 0, 0);
                u16 h0, h1, h2, h3;
                {
                    float e0 = exp2f(fminf(c[0] * SCL, 40.0f));
                    float e1 = exp2f(fminf(c[1] * SCL, 40.0f));
                    float e2 = exp2f(fminf(c[2] * SCL, 40.0f));
                    float e3 = exp2f(fminf(c[3] * SCL, 40.0f));
                    l1 += (e0 + e1) + (e2 + e3);
                    h0 = f2bf(e0); h1 = f2bf(e1); h2 = f2bf(e2); h3 = f2bf(e3);
                }
                uint2 pk;
                pk.x = (unsigned)h0 | ((unsigned)h1 << 16);
                pk.y = (unsigned)h2 | ((unsigned)h3 << 16);
                *(uint2*)&Pb[col][half * 16 + quad * 4] = pk;    // P[query][key]
            } else {
                *(uint2*)&Pb[col][half * 16 + quad * 4] = (uint2){0u, 0u};
            }
        }
        __syncthreads();   // single wave: write->read ordering
        bf16x8 A1 = *(const bf16x8*)&Pb[col][quad * 8];          // A[m=query][k=key]

        // --- pos-stream e2 directly in A-layout ---
        u16 eh[8];
        #pragma unroll
        for (int j = 0; j < 8; ++j) {
            const int m = key0 + quad * 8 + j;
            float e = 0.0f;
            if (m < NPAT) {
                int my = (m * 37450) >> 20;        // exact /28 for m < 800
                int mx = m - my * SGRID;
                float fdx = (float)(mx - nx);
                float fdy = (float)(my - ny);
                float p = c0 * fdx + c1 * fdy + c2 * (fdx * fdx + fdy * fdy) + bp;
                e = exp2f(fminf(p, 40.0f));
                l2 += e;
            }
            eh[j] = f2bf(e);
        }
        union { bf16x8 v; u16 h[8]; } ua2;
        #pragma unroll
        for (int j = 0; j < 8; ++j) ua2.h[j] = eh[j];
        const bf16x8 A2 = ua2.v;

        // --- V B-frags from V^T: lane&15 = d, k = quad*8+j = key (contiguous 16B) ---
        const u16* vr = Vt + (size_t)col * NPAT + key0 + quad * 8;
        bf16x8 Vlo = *(const bf16x8*)(vr);
        bf16x8 Vhi = *(const bf16x8*)(vr + (size_t)16 * NPAT);
        // (tail group reads <=48B past slab into following ws region: finite, x0)

        a1lo = __builtin_amdgcn_mfma_f32_16x16x32_bf16(A1, Vlo, a1lo, 0, 0, 0);
        a1hi = __builtin_amdgcn_mfma_f32_16x16x32_bf16(A1, Vhi, a1hi, 0, 0, 0);
        a2lo = __builtin_amdgcn_mfma_f32_16x16x32_bf16(A2, Vlo, a2lo, 0, 0, 0);
        a2hi = __builtin_amdgcn_mfma_f32_16x16x32_bf16(A2, Vhi, a2hi, 0, 0, 0);
        __syncthreads();   // protect Pb before next group's writes
    }

    // --- denominators: reduce over quads (keys), then transpose to C-layout index ---
    l1 += __shfl_xor(l1, 16); l1 += __shfl_xor(l1, 32);
    l2 += __shfl_xor(l2, 16); l2 += __shfl_xor(l2, 32);

    #pragma unroll
    for (int r = 0; r < 4; ++r) {
        const int qq = quad * 4 + r;            // query row of acc reg r (C-layout)
        const float l1q = __shfl(l1, qq);       // lanes 0..15 hold l1 per query
        const float l2q = __shfl(l2, qq);
        const float w1 = (1.0f - g) / l1q;
        const float w2 = g / l2q;
        const int n = qt * 16 + qq;
        u16* op = ob + ((size_t)bb * NPAT + n) * KDIM + hh * HD;
        op[col]      = f2bf(w1 * a1lo[r] + w2 * a2lo[r]);
        op[col + 16] = f2bf(w1 * a1hi[r] + w2 * a2hi[r]);
    }
}

// ---------------- Output projection: out = A @ Wo^T + b, f32 store ------------
__global__ __launch_bounds__(256) void out_gemm(
    const u16* __restrict__ A,        // [6272][384] bf16 (attention output in ws)
    const float* __restrict__ Wo,     // [384][384] f32
    const float* __restrict__ bias,   // [384] f32
    float* __restrict__ out)          // [6272][384] f32
{
    __shared__ float As[BK][BM];
    __shared__ float Bs[BK][BN];

    const int tid = threadIdx.x;
    const int im0 = blockIdx.x * BM;
    const int jn0 = blockIdx.y * BN;
    const int tx = tid & 15, ty = tid >> 4;
    const int r  = tid >> 2;
    const int c8 = (tid & 3) << 3;

    float acc[4][4] = {};

    for (int k0 = 0; k0 < KDIM; k0 += BK) {
        {   // A is bf16 in ws
            uint4 ra = *(const uint4*)(A + (size_t)(im0 + r) * KDIM + k0 + c8);
            unsigned wa[4] = {ra.x, ra.y, ra.z, ra.w};
            #pragma unroll
            for (int q = 0; q < 4; ++q) {
                union { unsigned i; float f; } lo, hi;
                lo.i = (wa[q] & 0xffffu) << 16; hi.i = wa[q] & 0xffff0000u;
                As[c8 + 2*q + 0][r] = lo.f;
                As[c8 + 2*q + 1][r] = hi.f;
            }
        }
        float4 b0 = *(const float4*)(Wo + (size_t)(jn0 + r) * KDIM + k0 + c8);
        float4 b1 = *(const float4*)(Wo + (size_t)(jn0 + r) * KDIM + k0 + c8 + 4);
        Bs[c8+0][r] = b0.x; Bs[c8+1][r] = b0.y; Bs[c8+2][r] = b0.z; Bs[c8+3][r] = b0.w;
        Bs[c8+4][r] = b1.x; Bs[c8+5][r] = b1.y; Bs[c8+6][r] = b1.z; Bs[c8+7][r] = b1.w;
        __syncthreads();
        #pragma unroll
        for (int kk = 0; kk < BK; ++kk) {
            float4 a = *(const float4*)&As[kk][ty << 2];
            float4 b = *(const float4*)&Bs[kk][tx << 2];
            float av[4] = {a.x, a.y, a.z, a.w};
            float bv[4] = {b.x, b.y, b.z, b.w};
            #pragma unroll
            for (int i = 0; i < 4; ++i)
                #pragma unroll
                for (int j = 0; j < 4; ++j)
                    acc[i][j] += av[i] * bv[j];
        }
        __syncthreads();
    }

    const int j0 = jn0 + (tx << 2);
    float bv[4];
    #pragma unroll
    for (int j = 0; j < 4; ++j) bv[j] = bias[j0 + j];
    #pragma unroll
    for (int i = 0; i < 4; ++i) {
        int gi = im0 + (ty << 2) + i;
        float4 st = make_float4(acc[i][0] + bv[0], acc[i][1] + bv[1],
                                acc[i][2] + bv[2], acc[i][3] + bv[3]);
        *(float4*)&out[(size_t)gi * KDIM + j0] = st;
    }
}

extern "C" void kernel_launch(void* const* d_in, const int* in_sizes, int n_in,
                              void* d_out, int out_size, void* d_ws, size_t ws_size,
                              hipStream_t stream) {
    const float* x    = (const float*)d_in[0];
    const float* Wq   = (const float*)d_in[1];
    const float* Wk   = (const float*)d_in[2];
    const float* Wv   = (const float*)d_in[3];
    const float* Wpos = (const float*)d_in[4];
    const float* bpos = (const float*)d_in[5];
    const float* Wout = (const float*)d_in[6];
    const float* bout = (const float*)d_in[7];
    const float* gat  = (const float*)d_in[8];

    // ws layout (19.27 MB):
    //   u16 Q[96][784][32] | u16 K[96][784][32] | u16 V^T[96][32][784] | u16 ob[6272][384]
    u16* qkvb = (u16*)d_ws;
    u16* ob   = qkvb + (size_t)3 * 96 * NPAT * HD;

    qkv_gemm<<<dim3(MDIM / BM, KDIM / BN, 3), 256, 0, stream>>>(x, Wq, Wk, Wv, qkvb);
    attn_mfma<<<dim3(NPAT / 16, 96), 64, 0, stream>>>(qkvb, Wpos, bpos, gat, ob);
    out_gemm<<<dim3(MDIM / BM, KDIM / BN), 256, 0, stream>>>(ob, Wout, bout, (float*)d_out);
}

// Round 6
// 187.405 us; speedup vs baseline: 2.9963x; 1.4566x over previous
//
#include <hip/hip_runtime.h>
#include <hip/hip_bf16.h>

// GPSA (ConViT gated positional self-attention), B=8 N=784 DIM=384 H=12 d=32.
// f32 inputs, f32 output. Round-6: MFMA GEMMs + 4-wave attn blocks + pos-exp table.
//   pos_tab:  e2tab[h][dy+27][dx+27] = exp2(min(L2E*pos_logit, 40))  (150 KB)
//   qkv_gemm: MFMA 128x128x32 (4 waves x 64x64), f32->bf16 staging;
//             Q,K -> [96][784][32] bf16, V -> transposed [96][32][784] bf16
//   attn_mfma: 4 waves/block, per wave 16 queries x 784 keys, dual softmax:
//             S^T=K·Q^T mfma -> exp -> LDS roundtrip -> A-frag; e2 from table; PV mfma.
//   out_gemm: MFMA, A=bf16 ws, B=Wo f32->bf16 staged, f32 store + bias.
// Math: attn row-sum == 1 ((1-g)+g) -> renormalize skipped; logits bounded above
// -> single-pass softmax, exp2-domain, clamped at 40 as NaN insurance.

#define MDIM 6272   // B*N
#define KDIM 384    // DIM
#define NPAT 784
#define SGRID 28
#define NH 12
#define HD 32

typedef unsigned short u16;
typedef __attribute__((ext_vector_type(8))) short bf16x8;
typedef __attribute__((ext_vector_type(4))) float f32x4;

__device__ __forceinline__ u16 f2bf(float f) {
    union { float f; unsigned u; } v; v.f = f;
    unsigned u = v.u;
    u += 0x7fffu + ((u >> 16) & 1u);   // round-to-nearest-even
    return (u16)(u >> 16);
}
__device__ __forceinline__ unsigned pack2(float a, float b) {
    return (unsigned)f2bf(a) | ((unsigned)f2bf(b) << 16);
}

// ---------------- pos-stream exp table ---------------------------------------
__global__ __launch_bounds__(256) void pos_tab(
    const float* __restrict__ W_pos, const float* __restrict__ b_pos,
    float* __restrict__ tab)           // [12][56][56] f32
{
    const int hh = blockIdx.x;
    const float L2E = 1.4426950408889634f;
    const float c0 = W_pos[hh * 3 + 0] * L2E;
    const float c1 = W_pos[hh * 3 + 1] * L2E;
    const float c2 = W_pos[hh * 3 + 2] * L2E;
    const float bp = b_pos[hh] * L2E;
    for (int idx = threadIdx.x; idx < 3136; idx += 256) {
        int dyi = idx / 56;
        int dx  = (idx - dyi * 56) - 27;
        int dy  = dyi - 27;
        float fdx = (float)dx, fdy = (float)dy;
        float p = c0 * fdx + c1 * fdy + c2 * (fdx * fdx + fdy * fdy) + bp;
        tab[hh * 3136 + idx] = exp2f(fminf(p, 40.0f));
    }
}

// ---------------- QKV projection: MFMA, C = x @ W^T --------------------------
// block 128x128, 4 waves (2x2), wave tile 64x64, BK=32, K=384 -> 12 iters.
__global__ __launch_bounds__(256) void qkv_gemm(
    const float* __restrict__ x,    // [6272][384] f32
    const float* __restrict__ Wq,
    const float* __restrict__ Wk,
    const float* __restrict__ Wv,
    u16* __restrict__ outb)
{
    __shared__ u16 As[128 * 32];
    __shared__ u16 Bs[128 * 32];

    const int mat = blockIdx.z;
    const float* W = (mat == 0) ? Wq : (mat == 1) ? Wk : Wv;
    const size_t S = (size_t)96 * NPAT * HD;
    u16* dst = outb + (size_t)mat * S;

    const int tid = threadIdx.x;
    const int im0 = blockIdx.x * 128;
    const int jn0 = blockIdx.y * 128;
    const int wid = tid >> 6, lane = tid & 63;
    const int wm = wid & 1, wn = wid >> 1;
    const int col = lane & 15, quad = lane >> 4;
    const int srow = tid >> 1;              // staging row 0..127
    const int scg  = (tid & 1) * 16;        // staging col group 0/16

    f32x4 acc[4][4];
    #pragma unroll
    for (int i = 0; i < 4; ++i)
        #pragma unroll
        for (int j = 0; j < 4; ++j) acc[i][j] = (f32x4){0, 0, 0, 0};

    for (int k0 = 0; k0 < KDIM; k0 += 32) {
        const float* ap = x + (size_t)(im0 + srow) * KDIM + k0 + scg;
        const float* bp = W + (size_t)(jn0 + srow) * KDIM + k0 + scg;
        float4 av[4], bv[4];
        #pragma unroll
        for (int i = 0; i < 4; ++i) {
            av[i] = *(const float4*)(ap + 4 * i);
            bv[i] = *(const float4*)(bp + 4 * i);
        }
        __syncthreads();   // protect previous iteration's frag reads
        uint4 w0, w1;
        w0.x = pack2(av[0].x, av[0].y); w0.y = pack2(av[0].z, av[0].w);
        w0.z = pack2(av[1].x, av[1].y); w0.w = pack2(av[1].z, av[1].w);
        w1.x = pack2(av[2].x, av[2].y); w1.y = pack2(av[2].z, av[2].w);
        w1.z = pack2(av[3].x, av[3].y); w1.w = pack2(av[3].z, av[3].w);
        *(uint4*)&As[srow * 32 + scg]     = w0;
        *(uint4*)&As[srow * 32 + scg + 8] = w1;
        w0.x = pack2(bv[0].x, bv[0].y); w0.y = pack2(bv[0].z, bv[0].w);
        w0.z = pack2(bv[1].x, bv[1].y); w0.w = pack2(bv[1].z, bv[1].w);
        w1.x = pack2(bv[2].x, bv[2].y); w1.y = pack2(bv[2].z, bv[2].w);
        w1.z = pack2(bv[3].x, bv[3].y); w1.w = pack2(bv[3].z, bv[3].w);
        *(uint4*)&Bs[srow * 32 + scg]     = w0;
        *(uint4*)&Bs[srow * 32 + scg + 8] = w1;
        __syncthreads();
        bf16x8 af[4], bf[4];
        #pragma unroll
        for (int it = 0; it < 4; ++it)
            af[it] = *(const bf16x8*)&As[(wm * 64 + it * 16 + col) * 32 + quad * 8];
        #pragma unroll
        for (int jt = 0; jt < 4; ++jt)
            bf[jt] = *(const bf16x8*)&Bs[(wn * 64 + jt * 16 + col) * 32 + quad * 8];
        #pragma unroll
        for (int it = 0; it < 4; ++it)
            #pragma unroll
            for (int jt = 0; jt < 4; ++jt)
                acc[it][jt] = __builtin_amdgcn_mfma_f32_16x16x32_bf16(af[it], bf[jt], acc[it][jt], 0, 0, 0);
    }

    // C[m][n]: m = im0+wm*64+it*16+quad*4+r (token), n = jn0+wn*64+jt*16+col (h*32+d)
    if (mat < 2) {
        #pragma unroll
        for (int it = 0; it < 4; ++it) {
            #pragma unroll
            for (int r = 0; r < 4; ++r) {
                int gi = im0 + wm * 64 + it * 16 + quad * 4 + r;
                int bb = gi / NPAT;
                int nn = gi - bb * NPAT;
                #pragma unroll
                for (int jt = 0; jt < 4; ++jt) {
                    int j = jn0 + wn * 64 + jt * 16 + col;
                    int hh = j >> 5, d0 = j & 31;
                    dst[(((size_t)bb * NH + hh) * NPAT + nn) * HD + d0] = f2bf(acc[it][jt][r]);
                }
            }
        }
    } else {
        // V^T[bh][d][n]: per lane 4 consecutive tokens -> ushort4
        #pragma unroll
        for (int it = 0; it < 4; ++it) {
            int gi0 = im0 + wm * 64 + it * 16 + quad * 4;
            int bb = gi0 / NPAT;
            int nn = gi0 - bb * NPAT;       // 4-aligned: never crosses batch (784%4==0)
            #pragma unroll
            for (int jt = 0; jt < 4; ++jt) {
                int j = jn0 + wn * 64 + jt * 16 + col;
                int hh = j >> 5, d0 = j & 31;
                ushort4 st;
                st.x = f2bf(acc[it][jt][0]); st.y = f2bf(acc[it][jt][1]);
                st.z = f2bf(acc[it][jt][2]); st.w = f2bf(acc[it][jt][3]);
                *(ushort4*)&dst[(((size_t)bb * NH + hh) * HD + d0) * NPAT + nn] = st;
            }
        }
    }
}

// ---------------- MFMA dual-softmax attention --------------------------------
// 4 waves/block; each wave: 16 queries x all 784 keys for one (b,h).
__global__ __launch_bounds__(256) void attn_mfma(
    const u16* __restrict__ qkvb,      // Q | K [96][784][32], V^T [96][32][784]
    const float* __restrict__ gating,  // [12] f32
    const float* __restrict__ e2tab,   // [12][56][56] f32
    u16* __restrict__ ob)              // [6272][384] bf16, [b][n][h*32+d]
{
    __shared__ u16 Pb[4][16][40];      // per-wave e1 staging, padded stride 40

    const int wid = threadIdx.x >> 6;
    const int lane = threadIdx.x & 63;
    int qt = blockIdx.x * 4 + wid;
    if (qt > 48) qt = 48;              // duplicate work, identical stores (benign)
    const int bh = blockIdx.y;
    const int bb = bh / NH;
    const int hh = bh - bb * NH;
    const int col = lane & 15;
    const int quad = lane >> 4;

    const float L2E = 1.4426950408889634f;
    const float SCL = 0.28867513459481287f * L2E;   // 12^-0.5 * log2(e)
    const float g = 1.0f / (1.0f + __expf(-gating[hh]));
    const float* tabh = e2tab + hh * 3136;

    const size_t S = (size_t)96 * NPAT * HD;
    const u16* Qp = qkvb + (size_t)bh * NPAT * HD;
    const u16* Kp = Qp + S;
    const u16* Vt = qkvb + 2 * S + (size_t)bh * HD * NPAT;

    const int q_n = qt * 16 + col;
    const int ny = q_n / SGRID;
    const int nx = q_n - ny * SGRID;

    const bf16x8 qf = *(const bf16x8*)(Qp + (size_t)q_n * HD + quad * 8);

    f32x4 a1lo = {0,0,0,0}, a1hi = {0,0,0,0};
    f32x4 a2lo = {0,0,0,0}, a2hi = {0,0,0,0};
    float l1 = 0.0f, l2 = 0.0f;

    for (int G = 0; G < 25; ++G) {
        const int key0 = G * 32;

        #pragma unroll
        for (int half = 0; half < 2; ++half) {
            const int kt = key0 + half * 16;
            if (kt < NPAT) {
                bf16x8 kf = *(const bf16x8*)(Kp + (size_t)(kt + col) * HD + quad * 8);
                f32x4 c = __builtin_amdgcn_mfma_f32_16x16x32_bf16(kf, qf, (f32x4){0,0,0,0}, 0, 0, 0);
                float e0 = exp2f(fminf(c[0] * SCL, 40.0f));
                float e1 = exp2f(fminf(c[1] * SCL, 40.0f));
                float e2 = exp2f(fminf(c[2] * SCL, 40.0f));
                float e3 = exp2f(fminf(c[3] * SCL, 40.0f));
                l1 += (e0 + e1) + (e2 + e3);
                uint2 pk;
                pk.x = pack2(e0, e1);
                pk.y = pack2(e2, e3);
                *(uint2*)&Pb[wid][col][half * 16 + quad * 4] = pk;
            } else {
                *(uint2*)&Pb[wid][col][half * 16 + quad * 4] = (uint2){0u, 0u};
            }
        }
        __syncthreads();
        bf16x8 A1 = *(const bf16x8*)&Pb[wid][col][quad * 8];

        // pos-stream e2 from table, built directly in A-layout
        u16 eh[8];
        #pragma unroll
        for (int j = 0; j < 8; ++j) {
            const int m = key0 + quad * 8 + j;
            float e = 0.0f;
            if (m < NPAT) {
                int my = (m * 37450) >> 20;        // exact /28 for m < 800
                int mx = m - my * SGRID;
                e = tabh[(my - ny + 27) * 56 + (mx - nx + 27)];
                l2 += e;
            }
            eh[j] = f2bf(e);
        }
        union { bf16x8 v; u16 h[8]; } ua2;
        #pragma unroll
        for (int j = 0; j < 8; ++j) ua2.h[j] = eh[j];
        const bf16x8 A2 = ua2.v;

        const u16* vr = Vt + (size_t)col * NPAT + key0 + quad * 8;
        bf16x8 Vlo = *(const bf16x8*)(vr);
        bf16x8 Vhi = *(const bf16x8*)(vr + (size_t)16 * NPAT);
        // tail overread (<=32B past slab) multiplies zeroed P entries: benign

        a1lo = __builtin_amdgcn_mfma_f32_16x16x32_bf16(A1, Vlo, a1lo, 0, 0, 0);
        a1hi = __builtin_amdgcn_mfma_f32_16x16x32_bf16(A1, Vhi, a1hi, 0, 0, 0);
        a2lo = __builtin_amdgcn_mfma_f32_16x16x32_bf16(A2, Vlo, a2lo, 0, 0, 0);
        a2hi = __builtin_amdgcn_mfma_f32_16x16x32_bf16(A2, Vhi, a2hi, 0, 0, 0);
        __syncthreads();
    }

    l1 += __shfl_xor(l1, 16); l1 += __shfl_xor(l1, 32);
    l2 += __shfl_xor(l2, 16); l2 += __shfl_xor(l2, 32);

    #pragma unroll
    for (int r = 0; r < 4; ++r) {
        const int qq = quad * 4 + r;
        const float l1q = __shfl(l1, qq);
        const float l2q = __shfl(l2, qq);
        const float w1 = (1.0f - g) / l1q;
        const float w2 = g / l2q;
        const int n = qt * 16 + qq;
        u16* op = ob + ((size_t)bb * NPAT + n) * KDIM + hh * HD;
        op[col]      = f2bf(w1 * a1lo[r] + w2 * a2lo[r]);
        op[col + 16] = f2bf(w1 * a1hi[r] + w2 * a2hi[r]);
    }
}

// ---------------- Output projection: MFMA, out = A @ Wo^T + b, f32 store -----
__global__ __launch_bounds__(256) void out_gemm(
    const u16* __restrict__ A,        // [6272][384] bf16 (attention output in ws)
    const float* __restrict__ Wo,     // [384][384] f32
    const float* __restrict__ bias,   // [384] f32
    float* __restrict__ out)          // [6272][384] f32
{
    __shared__ u16 As[128 * 32];
    __shared__ u16 Bs[128 * 32];

    const int tid = threadIdx.x;
    const int im0 = blockIdx.x * 128;
    const int jn0 = blockIdx.y * 128;
    const int wid = tid >> 6, lane = tid & 63;
    const int wm = wid & 1, wn = wid >> 1;
    const int col = lane & 15, quad = lane >> 4;
    const int srow = tid >> 1;
    const int scg  = (tid & 1) * 16;

    f32x4 acc[4][4];
    #pragma unroll
    for (int i = 0; i < 4; ++i)
        #pragma unroll
        for (int j = 0; j < 4; ++j) acc[i][j] = (f32x4){0, 0, 0, 0};

    for (int k0 = 0; k0 < KDIM; k0 += 32) {
        const u16* ap = A + (size_t)(im0 + srow) * KDIM + k0 + scg;
        uint4 ra0 = *(const uint4*)(ap);
        uint4 ra1 = *(const uint4*)(ap + 8);
        const float* bp = Wo + (size_t)(jn0 + srow) * KDIM + k0 + scg;
        float4 bv[4];
        #pragma unroll
        for (int i = 0; i < 4; ++i) bv[i] = *(const float4*)(bp + 4 * i);
        __syncthreads();
        *(uint4*)&As[srow * 32 + scg]     = ra0;
        *(uint4*)&As[srow * 32 + scg + 8] = ra1;
        uint4 w0, w1;
        w0.x = pack2(bv[0].x, bv[0].y); w0.y = pack2(bv[0].z, bv[0].w);
        w0.z = pack2(bv[1].x, bv[1].y); w0.w = pack2(bv[1].z, bv[1].w);
        w1.x = pack2(bv[2].x, bv[2].y); w1.y = pack2(bv[2].z, bv[2].w);
        w1.z = pack2(bv[3].x, bv[3].y); w1.w = pack2(bv[3].z, bv[3].w);
        *(uint4*)&Bs[srow * 32 + scg]     = w0;
        *(uint4*)&Bs[srow * 32 + scg + 8] = w1;
        __syncthreads();
        bf16x8 af[4], bf[4];
        #pragma unroll
        for (int it = 0; it < 4; ++it)
            af[it] = *(const bf16x8*)&As[(wm * 64 + it * 16 + col) * 32 + quad * 8];
        #pragma unroll
        for (int jt = 0; jt < 4; ++jt)
            bf[jt] = *(const bf16x8*)&Bs[(wn * 64 + jt * 16 + col) * 32 + quad * 8];
        #pragma unroll
        for (int it = 0; it < 4; ++it)
            #pragma unroll
            for (int jt = 0; jt < 4; ++jt)
                acc[it][jt] = __builtin_amdgcn_mfma_f32_16x16x32_bf16(af[it], bf[jt], acc[it][jt], 0, 0, 0);
    }

    float bvv[4];
    #pragma unroll
    for (int jt = 0; jt < 4; ++jt) bvv[jt] = bias[jn0 + wn * 64 + jt * 16 + col];
    #pragma unroll
    for (int it = 0; it < 4; ++it) {
        #pragma unroll
        for (int r = 0; r < 4; ++r) {
            int gi = im0 + wm * 64 + it * 16 + quad * 4 + r;
            #pragma unroll
            for (int jt = 0; jt < 4; ++jt) {
                int j = jn0 + wn * 64 + jt * 16 + col;
                out[(size_t)gi * KDIM + j] = acc[it][jt][r] + bvv[jt];
            }
        }
    }
}

extern "C" void kernel_launch(void* const* d_in, const int* in_sizes, int n_in,
                              void* d_out, int out_size, void* d_ws, size_t ws_size,
                              hipStream_t stream) {
    const float* x    = (const float*)d_in[0];
    const float* Wq   = (const float*)d_in[1];
    const float* Wk   = (const float*)d_in[2];
    const float* Wv   = (const float*)d_in[3];
    const float* Wpos = (const float*)d_in[4];
    const float* bpos = (const float*)d_in[5];
    const float* Wout = (const float*)d_in[6];
    const float* bout = (const float*)d_in[7];
    const float* gat  = (const float*)d_in[8];

    // ws layout (19.42 MB):
    //   u16 Q[96][784][32] | K | V^T[96][32][784]   = 14,450,688 B
    //   u16 ob[6272][384]                            =  4,816,896 B
    //   f32 e2tab[12][56][56]                        =    150,528 B
    u16* qkvb = (u16*)d_ws;
    u16* ob   = qkvb + (size_t)3 * 96 * NPAT * HD;
    float* e2tab = (float*)((char*)d_ws + 14450688 + 4816896);

    pos_tab<<<12, 256, 0, stream>>>(Wpos, bpos, e2tab);
    qkv_gemm<<<dim3(MDIM / 128, KDIM / 128, 3), 256, 0, stream>>>(x, Wq, Wk, Wv, qkvb);
    attn_mfma<<<dim3(13, 96), 256, 0, stream>>>(qkvb, gat, e2tab, ob);
    out_gemm<<<dim3(MDIM / 128, KDIM / 128), 256, 0, stream>>>(ob, Wout, bout, (float*)d_out);
}

// Round 7
// 183.994 us; speedup vs baseline: 3.0518x; 1.0185x over previous
//
#include <hip/hip_runtime.h>
#include <hip/hip_bf16.h>

// GPSA (ConViT gated positional self-attention), B=8 N=784 DIM=384 H=12 d=32.
// f32 inputs, f32 output. Round-7: attn de-VALU + XCD locality.
//   pos_tab:  bf16 exp-table [12][56][56] + precomputed l2[12][784] (784-box sums)
//   qkv_gemm: MFMA 128x128x32 (unchanged from R6)
//   attn_mfma: grid (bh=96, 13) -> XCD=bh%8 pins all qt-blocks of a bh to one XCD;
//              NO intra-loop barriers (Pb is per-wave; same-wave DS ops are in-order);
//              e2 loaded as bf16 (no f2bf), l2 from table (no accumulation/shuffles).
//   out_gemm: MFMA (unchanged).
// Math: attn row-sum == 1 ((1-g)+g) -> renormalize skipped; logits bounded above
// -> single-pass softmax, exp2-domain, clamped at 40 as NaN insurance.

#define MDIM 6272   // B*N
#define KDIM 384    // DIM
#define NPAT 784
#define SGRID 28
#define NH 12
#define HD 32

typedef unsigned short u16;
typedef __attribute__((ext_vector_type(8))) short bf16x8;
typedef __attribute__((ext_vector_type(4))) float f32x4;

__device__ __forceinline__ u16 f2bf(float f) {
    union { float f; unsigned u; } v; v.f = f;
    unsigned u = v.u;
    u += 0x7fffu + ((u >> 16) & 1u);   // round-to-nearest-even
    return (u16)(u >> 16);
}
__device__ __forceinline__ unsigned pack2(float a, float b) {
    return (unsigned)f2bf(a) | ((unsigned)f2bf(b) << 16);
}

// ---------------- pos-stream tables: bf16 exp + f32 row-sums -----------------
__global__ __launch_bounds__(256) void pos_tab(
    const float* __restrict__ W_pos, const float* __restrict__ b_pos,
    u16* __restrict__ tab_bf,          // [12][56][56] bf16
    float* __restrict__ l2tab)         // [12][784] f32
{
    __shared__ float tl[3136];
    const int hh = blockIdx.x;
    const float L2E = 1.4426950408889634f;
    const float c0 = W_pos[hh * 3 + 0] * L2E;
    const float c1 = W_pos[hh * 3 + 1] * L2E;
    const float c2 = W_pos[hh * 3 + 2] * L2E;
    const float bp = b_pos[hh] * L2E;
    for (int idx = threadIdx.x; idx < 3136; idx += 256) {
        int dyi = idx / 56;
        int dx  = (idx - dyi * 56) - 27;
        int dy  = dyi - 27;
        float fdx = (float)dx, fdy = (float)dy;
        float p = c0 * fdx + c1 * fdy + c2 * (fdx * fdx + fdy * fdy) + bp;
        float e = exp2f(fminf(p, 40.0f));
        tl[idx] = e;
        tab_bf[hh * 3136 + idx] = f2bf(e);
    }
    __syncthreads();
    for (int n = threadIdx.x; n < NPAT; n += 256) {
        int ny = n / SGRID;
        int nx = n - ny * SGRID;
        float s = 0.0f;
        const float* base = &tl[(27 - ny) * 56 + (27 - nx)];
        #pragma unroll 4
        for (int my = 0; my < SGRID; ++my) {
            const float* row = base + my * 56;
            #pragma unroll
            for (int mx = 0; mx < SGRID; ++mx) s += row[mx];
        }
        l2tab[hh * NPAT + n] = s;
    }
}

// ---------------- QKV projection: MFMA, C = x @ W^T --------------------------
__global__ __launch_bounds__(256) void qkv_gemm(
    const float* __restrict__ x,    // [6272][384] f32
    const float* __restrict__ Wq,
    const float* __restrict__ Wk,
    const float* __restrict__ Wv,
    u16* __restrict__ outb)
{
    __shared__ u16 As[128 * 32];
    __shared__ u16 Bs[128 * 32];

    const int mat = blockIdx.z;
    const float* W = (mat == 0) ? Wq : (mat == 1) ? Wk : Wv;
    const size_t S = (size_t)96 * NPAT * HD;
    u16* dst = outb + (size_t)mat * S;

    const int tid = threadIdx.x;
    const int im0 = blockIdx.x * 128;
    const int jn0 = blockIdx.y * 128;
    const int wid = tid >> 6, lane = tid & 63;
    const int wm = wid & 1, wn = wid >> 1;
    const int col = lane & 15, quad = lane >> 4;
    const int srow = tid >> 1;
    const int scg  = (tid & 1) * 16;

    f32x4 acc[4][4];
    #pragma unroll
    for (int i = 0; i < 4; ++i)
        #pragma unroll
        for (int j = 0; j < 4; ++j) acc[i][j] = (f32x4){0, 0, 0, 0};

    for (int k0 = 0; k0 < KDIM; k0 += 32) {
        const float* ap = x + (size_t)(im0 + srow) * KDIM + k0 + scg;
        const float* bp = W + (size_t)(jn0 + srow) * KDIM + k0 + scg;
        float4 av[4], bv[4];
        #pragma unroll
        for (int i = 0; i < 4; ++i) {
            av[i] = *(const float4*)(ap + 4 * i);
            bv[i] = *(const float4*)(bp + 4 * i);
        }
        __syncthreads();
        uint4 w0, w1;
        w0.x = pack2(av[0].x, av[0].y); w0.y = pack2(av[0].z, av[0].w);
        w0.z = pack2(av[1].x, av[1].y); w0.w = pack2(av[1].z, av[1].w);
        w1.x = pack2(av[2].x, av[2].y); w1.y = pack2(av[2].z, av[2].w);
        w1.z = pack2(av[3].x, av[3].y); w1.w = pack2(av[3].z, av[3].w);
        *(uint4*)&As[srow * 32 + scg]     = w0;
        *(uint4*)&As[srow * 32 + scg + 8] = w1;
        w0.x = pack2(bv[0].x, bv[0].y); w0.y = pack2(bv[0].z, bv[0].w);
        w0.z = pack2(bv[1].x, bv[1].y); w0.w = pack2(bv[1].z, bv[1].w);
        w1.x = pack2(bv[2].x, bv[2].y); w1.y = pack2(bv[2].z, bv[2].w);
        w1.z = pack2(bv[3].x, bv[3].y); w1.w = pack2(bv[3].z, bv[3].w);
        *(uint4*)&Bs[srow * 32 + scg]     = w0;
        *(uint4*)&Bs[srow * 32 + scg + 8] = w1;
        __syncthreads();
        bf16x8 af[4], bf[4];
        #pragma unroll
        for (int it = 0; it < 4; ++it)
            af[it] = *(const bf16x8*)&As[(wm * 64 + it * 16 + col) * 32 + quad * 8];
        #pragma unroll
        for (int jt = 0; jt < 4; ++jt)
            bf[jt] = *(const bf16x8*)&Bs[(wn * 64 + jt * 16 + col) * 32 + quad * 8];
        #pragma unroll
        for (int it = 0; it < 4; ++it)
            #pragma unroll
            for (int jt = 0; jt < 4; ++jt)
                acc[it][jt] = __builtin_amdgcn_mfma_f32_16x16x32_bf16(af[it], bf[jt], acc[it][jt], 0, 0, 0);
    }

    if (mat < 2) {
        #pragma unroll
        for (int it = 0; it < 4; ++it) {
            #pragma unroll
            for (int r = 0; r < 4; ++r) {
                int gi = im0 + wm * 64 + it * 16 + quad * 4 + r;
                int bb = gi / NPAT;
                int nn = gi - bb * NPAT;
                #pragma unroll
                for (int jt = 0; jt < 4; ++jt) {
                    int j = jn0 + wn * 64 + jt * 16 + col;
                    int hh = j >> 5, d0 = j & 31;
                    dst[(((size_t)bb * NH + hh) * NPAT + nn) * HD + d0] = f2bf(acc[it][jt][r]);
                }
            }
        }
    } else {
        #pragma unroll
        for (int it = 0; it < 4; ++it) {
            int gi0 = im0 + wm * 64 + it * 16 + quad * 4;
            int bb = gi0 / NPAT;
            int nn = gi0 - bb * NPAT;       // 4-aligned: never crosses batch
            #pragma unroll
            for (int jt = 0; jt < 4; ++jt) {
                int j = jn0 + wn * 64 + jt * 16 + col;
                int hh = j >> 5, d0 = j & 31;
                ushort4 st;
                st.x = f2bf(acc[it][jt][0]); st.y = f2bf(acc[it][jt][1]);
                st.z = f2bf(acc[it][jt][2]); st.w = f2bf(acc[it][jt][3]);
                *(ushort4*)&dst[(((size_t)bb * NH + hh) * HD + d0) * NPAT + nn] = st;
            }
        }
    }
}

// ---------------- MFMA dual-softmax attention --------------------------------
// grid (96, 13): blockIdx.x = bh (XCD = bh%8 -> K/V L2 locality); 4 waves/block,
// wave handles qt = blockIdx.y*4+wid (clamped; dup waves store identical data).
// No intra-loop barriers: Pb is per-wave, same-wave DS ops are in-order.
__global__ __launch_bounds__(256) void attn_mfma(
    const u16* __restrict__ qkvb,      // Q | K [96][784][32], V^T [96][32][784]
    const float* __restrict__ gating,  // [12] f32
    const u16* __restrict__ tab_bf,    // [12][56][56] bf16
    const float* __restrict__ l2tab,   // [12][784] f32
    u16* __restrict__ ob)              // [6272][384] bf16, [b][n][h*32+d]
{
    __shared__ u16 Pb[4][16][40];      // per-wave e1 staging, padded stride 40

    const int wid = threadIdx.x >> 6;
    const int lane = threadIdx.x & 63;
    const int bh = blockIdx.x;
    int qt = blockIdx.y * 4 + wid;
    if (qt > 48) qt = 48;
    const int bb = bh / NH;
    const int hh = bh - bb * NH;
    const int col = lane & 15;
    const int quad = lane >> 4;

    const float L2E = 1.4426950408889634f;
    const float SCL = 0.28867513459481287f * L2E;   // 12^-0.5 * log2(e)
    const float g = 1.0f / (1.0f + __expf(-gating[hh]));
    const u16* tabh = tab_bf + hh * 3136;

    const size_t S = (size_t)96 * NPAT * HD;
    const u16* Qp = qkvb + (size_t)bh * NPAT * HD;
    const u16* Kp = Qp + S;
    const u16* Vt = qkvb + 2 * S + (size_t)bh * HD * NPAT;

    const int q_n = qt * 16 + col;
    const int ny = q_n / SGRID;
    const int nx = q_n - ny * SGRID;
    const int tbase = (27 - ny) * 56 + (27 - nx);   // + my*56 + mx

    const bf16x8 qf = *(const bf16x8*)(Qp + (size_t)q_n * HD + quad * 8);

    f32x4 a1lo = {0,0,0,0}, a1hi = {0,0,0,0};
    f32x4 a2lo = {0,0,0,0}, a2hi = {0,0,0,0};
    float l1 = 0.0f;

    for (int G = 0; G < 25; ++G) {
        const int key0 = G * 32;

        #pragma unroll
        for (int half = 0; half < 2; ++half) {
            const int kt = key0 + half * 16;
            if (kt < NPAT) {
                bf16x8 kf = *(const bf16x8*)(Kp + (size_t)(kt + col) * HD + quad * 8);
                f32x4 c = __builtin_amdgcn_mfma_f32_16x16x32_bf16(kf, qf, (f32x4){0,0,0,0}, 0, 0, 0);
                float e0 = exp2f(fminf(c[0] * SCL, 40.0f));
                float e1 = exp2f(fminf(c[1] * SCL, 40.0f));
                float e2 = exp2f(fminf(c[2] * SCL, 40.0f));
                float e3 = exp2f(fminf(c[3] * SCL, 40.0f));
                l1 += (e0 + e1) + (e2 + e3);
                uint2 pk;
                pk.x = pack2(e0, e1);
                pk.y = pack2(e2, e3);
                *(uint2*)&Pb[wid][col][half * 16 + quad * 4] = pk;
            } else {
                *(uint2*)&Pb[wid][col][half * 16 + quad * 4] = (uint2){0u, 0u};
            }
        }
        // same-wave DS ordering: reads below see this wave's writes above
        bf16x8 A1 = *(const bf16x8*)&Pb[wid][col][quad * 8];

        // pos-stream e2: direct bf16 gathers, incremental (mx,my)
        const int m0 = key0 + quad * 8;
        int my0 = (m0 * 37450) >> 20;              // exact /28 for m < 800
        int mx0 = m0 - my0 * SGRID;
        u16 eh[8];
        #pragma unroll
        for (int j = 0; j < 8; ++j) {
            int mxj = mx0 + j, myj = my0;
            if (mxj >= SGRID) { mxj -= SGRID; ++myj; }
            eh[j] = (m0 + j < NPAT) ? tabh[tbase + myj * 56 + mxj] : (u16)0;
        }
        union { bf16x8 v; u16 h[8]; } ua2;
        #pragma unroll
        for (int j = 0; j < 8; ++j) ua2.h[j] = eh[j];
        const bf16x8 A2 = ua2.v;

        const u16* vr = Vt + (size_t)col * NPAT + key0 + quad * 8;
        bf16x8 Vlo = *(const bf16x8*)(vr);
        bf16x8 Vhi = *(const bf16x8*)(vr + (size_t)16 * NPAT);
        // tail overread (<=32B past slab) multiplies zeroed P entries: benign

        a1lo = __builtin_amdgcn_mfma_f32_16x16x32_bf16(A1, Vlo, a1lo, 0, 0, 0);
        a1hi = __builtin_amdgcn_mfma_f32_16x16x32_bf16(A1, Vhi, a1hi, 0, 0, 0);
        a2lo = __builtin_amdgcn_mfma_f32_16x16x32_bf16(A2, Vlo, a2lo, 0, 0, 0);
        a2hi = __builtin_amdgcn_mfma_f32_16x16x32_bf16(A2, Vhi, a2hi, 0, 0, 0);
    }

    l1 += __shfl_xor(l1, 16); l1 += __shfl_xor(l1, 32);

    #pragma unroll
    for (int r = 0; r < 4; ++r) {
        const int qq = quad * 4 + r;
        const int n = qt * 16 + qq;
        const float l1q = __shfl(l1, qq);
        const float l2q = l2tab[hh * NPAT + n];
        const float w1 = (1.0f - g) / l1q;
        const float w2 = g / l2q;
        u16* op = ob + ((size_t)bb * NPAT + n) * KDIM + hh * HD;
        op[col]      = f2bf(w1 * a1lo[r] + w2 * a2lo[r]);
        op[col + 16] = f2bf(w1 * a1hi[r] + w2 * a2hi[r]);
    }
}

// ---------------- Output projection: MFMA, out = A @ Wo^T + b, f32 store -----
__global__ __launch_bounds__(256) void out_gemm(
    const u16* __restrict__ A,        // [6272][384] bf16 (attention output in ws)
    const float* __restrict__ Wo,     // [384][384] f32
    const float* __restrict__ bias,   // [384] f32
    float* __restrict__ out)          // [6272][384] f32
{
    __shared__ u16 As[128 * 32];
    __shared__ u16 Bs[128 * 32];

    const int tid = threadIdx.x;
    const int im0 = blockIdx.x * 128;
    const int jn0 = blockIdx.y * 128;
    const int wid = tid >> 6, lane = tid & 63;
    const int wm = wid & 1, wn = wid >> 1;
    const int col = lane & 15, quad = lane >> 4;
    const int srow = tid >> 1;
    const int scg  = (tid & 1) * 16;

    f32x4 acc[4][4];
    #pragma unroll
    for (int i = 0; i < 4; ++i)
        #pragma unroll
        for (int j = 0; j < 4; ++j) acc[i][j] = (f32x4){0, 0, 0, 0};

    for (int k0 = 0; k0 < KDIM; k0 += 32) {
        const u16* ap = A + (size_t)(im0 + srow) * KDIM + k0 + scg;
        uint4 ra0 = *(const uint4*)(ap);
        uint4 ra1 = *(const uint4*)(ap + 8);
        const float* bp = Wo + (size_t)(jn0 + srow) * KDIM + k0 + scg;
        float4 bv[4];
        #pragma unroll
        for (int i = 0; i < 4; ++i) bv[i] = *(const float4*)(bp + 4 * i);
        __syncthreads();
        *(uint4*)&As[srow * 32 + scg]     = ra0;
        *(uint4*)&As[srow * 32 + scg + 8] = ra1;
        uint4 w0, w1;
        w0.x = pack2(bv[0].x, bv[0].y); w0.y = pack2(bv[0].z, bv[0].w);
        w0.z = pack2(bv[1].x, bv[1].y); w0.w = pack2(bv[1].z, bv[1].w);
        w1.x = pack2(bv[2].x, bv[2].y); w1.y = pack2(bv[2].z, bv[2].w);
        w1.z = pack2(bv[3].x, bv[3].y); w1.w = pack2(bv[3].z, bv[3].w);
        *(uint4*)&Bs[srow * 32 + scg]     = w0;
        *(uint4*)&Bs[srow * 32 + scg + 8] = w1;
        __syncthreads();
        bf16x8 af[4], bf[4];
        #pragma unroll
        for (int it = 0; it < 4; ++it)
            af[it] = *(const bf16x8*)&As[(wm * 64 + it * 16 + col) * 32 + quad * 8];
        #pragma unroll
        for (int jt = 0; jt < 4; ++jt)
            bf[jt] = *(const bf16x8*)&Bs[(wn * 64 + jt * 16 + col) * 32 + quad * 8];
        #pragma unroll
        for (int it = 0; it < 4; ++it)
            #pragma unroll
            for (int jt = 0; jt < 4; ++jt)
                acc[it][jt] = __builtin_amdgcn_mfma_f32_16x16x32_bf16(af[it], bf[jt], acc[it][jt], 0, 0, 0);
    }

    float bvv[4];
    #pragma unroll
    for (int jt = 0; jt < 4; ++jt) bvv[jt] = bias[jn0 + wn * 64 + jt * 16 + col];
    #pragma unroll
    for (int it = 0; it < 4; ++it) {
        #pragma unroll
        for (int r = 0; r < 4; ++r) {
            int gi = im0 + wm * 64 + it * 16 + quad * 4 + r;
            #pragma unroll
            for (int jt = 0; jt < 4; ++jt) {
                int j = jn0 + wn * 64 + jt * 16 + col;
                out[(size_t)gi * KDIM + j] = acc[it][jt][r] + bvv[jt];
            }
        }
    }
}

extern "C" void kernel_launch(void* const* d_in, const int* in_sizes, int n_in,
                              void* d_out, int out_size, void* d_ws, size_t ws_size,
                              hipStream_t stream) {
    const float* x    = (const float*)d_in[0];
    const float* Wq   = (const float*)d_in[1];
    const float* Wk   = (const float*)d_in[2];
    const float* Wv   = (const float*)d_in[3];
    const float* Wpos = (const float*)d_in[4];
    const float* bpos = (const float*)d_in[5];
    const float* Wout = (const float*)d_in[6];
    const float* bout = (const float*)d_in[7];
    const float* gat  = (const float*)d_in[8];

    // ws layout (~19.4 MB):
    //   u16 Q[96][784][32] | K | V^T[96][32][784]   = 14,450,688 B
    //   u16 ob[6272][384]                            =  4,816,896 B
    //   u16 tab_bf[12][56][56]                       =     75,264 B
    //   f32 l2tab[12][784]                           =     37,632 B
    u16* qkvb = (u16*)d_ws;
    u16* ob   = qkvb + (size_t)3 * 96 * NPAT * HD;
    u16* tab_bf = (u16*)((char*)d_ws + 14450688 + 4816896);
    float* l2tab = (float*)((char*)d_ws + 14450688 + 4816896 + 75264);

    pos_tab<<<12, 256, 0, stream>>>(Wpos, bpos, tab_bf, l2tab);
    qkv_gemm<<<dim3(MDIM / 128, KDIM / 128, 3), 256, 0, stream>>>(x, Wq, Wk, Wv, qkvb);
    attn_mfma<<<dim3(96, 13), 256, 0, stream>>>(qkvb, gat, tab_bf, l2tab, ob);
    out_gemm<<<dim3(MDIM / 128, KDIM / 128), 256, 0, stream>>>(ob, Wout, bout, (float*)d_out);
}